// Round 1
// baseline (47.291 us; speedup 1.0000x reference)
//
#include <hip/hip_runtime.h>

#define EPS 1e-12f

constexpr int B = 32, P = 1000, H = 128, D = 64;
constexpr int PT = 128;                    // p-tile per block
constexpr int TILES = (P + PT - 1) / PT;   // 8

__device__ __forceinline__ float fast_rcp(float x)  { return __builtin_amdgcn_rcpf(x); }
__device__ __forceinline__ float fast_sqrt(float x) { return __builtin_amdgcn_sqrtf(x); }

__global__ __launch_bounds__(256)
void ex2vec_kernel(const int* __restrict__ user_index,
                   const int* __restrict__ pred_items,
                   const int* __restrict__ hist_items,
                   const float* __restrict__ hist_td,
                   const float* __restrict__ hist_w,
                   const float* __restrict__ emb_user,
                   const float* __restrict__ emb_item,
                   const float* __restrict__ user_lamb,
                   const float* __restrict__ user_bias,
                   const float* __restrict__ item_bias,
                   const float* __restrict__ sc_global_lamb,
                   const float* __restrict__ sc_alpha,
                   const float* __restrict__ sc_beta,
                   const float* __restrict__ sc_gamma,
                   const float* __restrict__ sc_cutoff,
                   const float* __restrict__ sc_smooth,
                   const float* __restrict__ sc_force,
                   float* __restrict__ out)
{
    __shared__ float4 h_lds[H * (D / 4)];   // 32 KB: history embeddings for this b
    __shared__ float4 u_lds[D / 4];         // user embedding
    __shared__ float  hh[H];                // sum(h*h) per history row
    __shared__ float  td[H];                // (timedelta+cutoff)^-0.5 * weight

    const int b    = blockIdx.x >> 3;       // 8 tiles per b
    const int tile = blockIdx.x & 7;
    const int tid  = threadIdx.x;

    const int   uidx   = user_index[b];
    const float cutoff = *sc_cutoff;

    if (tid < D / 4)
        u_lds[tid] = ((const float4*)(emb_user + (size_t)uidx * D))[tid];

    // stage h rows (coalesced 16B per lane, contiguous within each row)
    for (int i = tid; i < H * (D / 4); i += 256) {
        const int h = i >> 4, k = i & 15;
        const int hidx = hist_items[b * H + h];
        h_lds[i] = ((const float4*)(emb_item + (size_t)hidx * D))[k];
    }
    // hh + td: re-read rows from global (L1/L2-hot) to avoid LDS column conflicts
    if (tid < H) {
        const int hidx = hist_items[b * H + tid];
        const float4* row = (const float4*)(emb_item + (size_t)hidx * D);
        float s = 0.f;
        #pragma unroll
        for (int k = 0; k < D / 4; ++k) {
            float4 v = row[k];
            s += v.x * v.x + v.y * v.y + v.z * v.z + v.w * v.w;
        }
        hh[tid] = s;
        td[tid] = hist_w[b * H + tid] / sqrtf(hist_td[b * H + tid] + cutoff);
    }
    __syncthreads();

    const int p_local = tid >> 1;
    const int hlf     = tid & 1;            // even/odd h split between the pair
    const int p       = tile * PT + p_local;
    if (p >= P) return;                     // no barriers after this point

    const int pidx = pred_items[b * P + p];
    const float4* prow = (const float4*)(emb_item + (size_t)pidx * D);

    float4 pv[D / 4];
    float pp = 0.f, duu = 0.f;
    #pragma unroll
    for (int k = 0; k < D / 4; ++k) {
        pv[k] = prow[k];
        float4 uv = u_lds[k];
        pp  += pv[k].x * pv[k].x + pv[k].y * pv[k].y + pv[k].z * pv[k].z + pv[k].w * pv[k].w;
        float dx = uv.x - pv[k].x, dy = uv.y - pv[k].y,
              dz = uv.z - pv[k].z, dw = uv.w - pv[k].w;
        duu += dx * dx + dy * dy + dz * dz + dw * dw;
    }
    const float dist_ui = fast_sqrt(duu + EPS);

    const float smooth    = *sc_smooth;
    const float fs        = *sc_force * smooth;
    // kern = sigmoid(x)/sigmoid(smooth-fs) = (1+exp(fs-smooth)) / (1+exp(-x))
    const float inv_denom = 1.f + __expf(fs - smooth);

    float acc = 0.f;
    #pragma unroll 2
    for (int j = 0; j < H / 2; ++j) {
        const int h = (j << 1) | hlf;       // 2 distinct LDS addresses per wave -> broadcast
        const float4* hr = &h_lds[h * (D / 4)];
        float d0 = 0.f, d1 = 0.f, d2 = 0.f, d3 = 0.f;   // 4 independent FMA chains
        #pragma unroll
        for (int k = 0; k < D / 4; ++k) {
            float4 hv = hr[k];
            d0 += hv.x * pv[k].x; d1 += hv.y * pv[k].y;
            d2 += hv.z * pv[k].z; d3 += hv.w * pv[k].w;
        }
        const float dot  = (d0 + d1) + (d2 + d3);
        const float sq   = hh[h] + pp - 2.f * dot;
        const float dist = fast_sqrt(fmaxf(sq, 0.f) + EPS);
        const float x    = smooth * fast_rcp(1.f + dist) - fs;
        acc += td[h] * (inv_denom * fast_rcp(1.f + __expf(-x)));
    }
    acc += __shfl_xor(acc, 1);              // combine even/odd h halves

    if (hlf == 0) {
        const float lamb = *sc_global_lamb + user_lamb[uidx];
        const float o    = fmaxf(0.f, dist_ui - lamb * acc);
        out[b * P + p] = *sc_alpha * o + *sc_beta * o * o + *sc_gamma
                         + user_bias[uidx] + item_bias[pidx];
    }
}

extern "C" void kernel_launch(void* const* d_in, const int* in_sizes, int n_in,
                              void* d_out, int out_size, void* d_ws, size_t ws_size,
                              hipStream_t stream) {
    (void)in_sizes; (void)n_in; (void)d_ws; (void)ws_size; (void)out_size;
    ex2vec_kernel<<<dim3(B * TILES), dim3(256), 0, stream>>>(
        (const int*)d_in[0],  (const int*)d_in[1],  (const int*)d_in[2],
        (const float*)d_in[3], (const float*)d_in[4],
        (const float*)d_in[5], (const float*)d_in[6],
        (const float*)d_in[7], (const float*)d_in[8], (const float*)d_in[9],
        (const float*)d_in[10], (const float*)d_in[11], (const float*)d_in[12],
        (const float*)d_in[13], (const float*)d_in[14], (const float*)d_in[15],
        (const float*)d_in[16], (float*)d_out);
}

// Round 2
// 21.263 us; speedup vs baseline: 2.2241x; 2.2241x over previous
//
#include <hip/hip_runtime.h>

#define EPS 1e-12f

constexpr int B = 32, P = 1000, H = 128, D = 64;
constexpr int PT = 64;                      // p-tile per block
constexpr int TILES = (P + PT - 1) / PT;    // 16 (last tile partial: 40 valid)
constexpr int NT = 512;                     // threads per block (8 waves)
constexpr int RS = 17;                      // padded row stride in float4 (68 dwords -> bank step 4)

__device__ __forceinline__ float fast_rcp(float x)  { return __builtin_amdgcn_rcpf(x); }
__device__ __forceinline__ float fast_sqrt(float x) { return __builtin_amdgcn_sqrtf(x); }

__device__ __forceinline__ float dot4(float4 a, float4 b, float acc) {
    acc = fmaf(a.x, b.x, acc); acc = fmaf(a.y, b.y, acc);
    acc = fmaf(a.z, b.z, acc); acc = fmaf(a.w, b.w, acc);
    return acc;
}

__global__ __launch_bounds__(NT, 4)
void ex2vec_kernel(const int* __restrict__ user_index,
                   const int* __restrict__ pred_items,
                   const int* __restrict__ hist_items,
                   const float* __restrict__ hist_td,
                   const float* __restrict__ hist_w,
                   const float* __restrict__ emb_user,
                   const float* __restrict__ emb_item,
                   const float* __restrict__ user_lamb,
                   const float* __restrict__ user_bias,
                   const float* __restrict__ item_bias,
                   const float* __restrict__ sc_global_lamb,
                   const float* __restrict__ sc_alpha,
                   const float* __restrict__ sc_beta,
                   const float* __restrict__ sc_gamma,
                   const float* __restrict__ sc_cutoff,
                   const float* __restrict__ sc_smooth,
                   const float* __restrict__ sc_force,
                   float* __restrict__ out)
{
    __shared__ float4 h_lds[H * RS];        // 34.0 KB padded
    __shared__ float4 p_lds[PT * RS];       // 17.0 KB padded
    __shared__ float4 u_lds[D / 4];
    __shared__ float  hh[H];
    __shared__ float  td_s[H];
    __shared__ float  pp[PT];
    __shared__ float  red[8 * PT];          // 8 waves x 64 p partials

    const int b    = blockIdx.x >> 4;
    const int tile = blockIdx.x & 15;
    const int tid  = threadIdx.x;

    const int   uidx   = user_index[b];
    const float cutoff = *sc_cutoff;

    // ---- stage h rows (128 x 64 f32), coalesced 16B/lane, 16 lanes per row ----
    for (int i = tid; i < H * 16; i += NT) {
        const int r = i >> 4, k = i & 15;
        const int hidx = hist_items[b * H + r];
        h_lds[r * RS + k] = ((const float4*)(emb_item + (size_t)hidx * D))[k];
    }
    // ---- stage p rows (64 x 64 f32), tail-clamped ----
    for (int i = tid; i < PT * 16; i += NT) {
        const int r = i >> 4, k = i & 15;
        int pg = tile * PT + r; pg = pg < P ? pg : P - 1;
        const int pidx = pred_items[b * P + pg];
        p_lds[r * RS + k] = ((const float4*)(emb_item + (size_t)pidx * D))[k];
    }
    // ---- prologue scalars, disjoint thread ranges ----
    if (tid < H) {                           // hh + td (rows hot in L1/L2)
        const int hidx = hist_items[b * H + tid];
        const float4* row = (const float4*)(emb_item + (size_t)hidx * D);
        float s = 0.f;
        #pragma unroll
        for (int k = 0; k < 16; ++k) {
            float4 v = row[k];
            s += v.x * v.x + v.y * v.y + v.z * v.z + v.w * v.w;
        }
        hh[tid]   = s;
        td_s[tid] = hist_w[b * H + tid] * __frsqrt_rn(hist_td[b * H + tid] + cutoff);
    } else if (tid < H + PT) {               // pp
        const int r = tid - H;
        int pg = tile * PT + r; pg = pg < P ? pg : P - 1;
        const int pidx = pred_items[b * P + pg];
        const float4* row = (const float4*)(emb_item + (size_t)pidx * D);
        float s = 0.f;
        #pragma unroll
        for (int k = 0; k < 16; ++k) {
            float4 v = row[k];
            s += v.x * v.x + v.y * v.y + v.z * v.z + v.w * v.w;
        }
        pp[r] = s;
    } else if (tid < H + PT + 16) {          // u
        const int k = tid - (H + PT);
        u_lds[k] = ((const float4*)(emb_user + (size_t)uidx * D))[k];
    }
    __syncthreads();

    // ---- 4h x 4p register tile per thread ----
    // hr = tid>>4 in [0,32): h rows {hr + 32i}.  pc = tid&15: p cols {pc + 16j}.
    const int hr = tid >> 4;
    const int pc = tid & 15;
    const float4* hp  = h_lds + hr * RS;
    const float4* ppr = p_lds + pc * RS;

    float acc[4][4] = {{0.f}};
    #pragma unroll 4
    for (int k = 0; k < 16; ++k) {
        float4 hv0 = hp[k],               hv1 = hp[k + 32 * RS],
               hv2 = hp[k + 64 * RS],     hv3 = hp[k + 96 * RS];
        float4 pv0 = ppr[k],              pv1 = ppr[k + 16 * RS],
               pv2 = ppr[k + 32 * RS],    pv3 = ppr[k + 48 * RS];
        acc[0][0] = dot4(hv0, pv0, acc[0][0]); acc[0][1] = dot4(hv0, pv1, acc[0][1]);
        acc[0][2] = dot4(hv0, pv2, acc[0][2]); acc[0][3] = dot4(hv0, pv3, acc[0][3]);
        acc[1][0] = dot4(hv1, pv0, acc[1][0]); acc[1][1] = dot4(hv1, pv1, acc[1][1]);
        acc[1][2] = dot4(hv1, pv2, acc[1][2]); acc[1][3] = dot4(hv1, pv3, acc[1][3]);
        acc[2][0] = dot4(hv2, pv0, acc[2][0]); acc[2][1] = dot4(hv2, pv1, acc[2][1]);
        acc[2][2] = dot4(hv2, pv2, acc[2][2]); acc[2][3] = dot4(hv2, pv3, acc[2][3]);
        acc[3][0] = dot4(hv3, pv0, acc[3][0]); acc[3][1] = dot4(hv3, pv1, acc[3][1]);
        acc[3][2] = dot4(hv3, pv2, acc[3][2]); acc[3][3] = dot4(hv3, pv3, acc[3][3]);
    }

    // ---- elementwise kernel + weighted h-sum (16 pairs/thread) ----
    const float smooth = *sc_smooth;
    const float fs     = *sc_force * smooth;
    // kern = sigmoid(x)/sigmoid(smooth-fs); fold inv_denom = 1+exp(fs-smooth) into lamb later
    float ppv[4];
    #pragma unroll
    for (int j = 0; j < 4; ++j) ppv[j] = pp[pc + 16 * j];

    float pres[4] = {0.f, 0.f, 0.f, 0.f};
    #pragma unroll
    for (int i = 0; i < 4; ++i) {
        const float tdv = td_s[hr + 32 * i];
        const float hhv = hh[hr + 32 * i];
        #pragma unroll
        for (int j = 0; j < 4; ++j) {
            const float sq   = hhv + ppv[j] - 2.f * acc[i][j];
            const float dist = fast_sqrt(fmaxf(sq, 0.f) + EPS);
            const float x    = smooth * fast_rcp(1.f + dist) - fs;
            pres[j] += tdv * fast_rcp(1.f + __expf(-x));
        }
    }

    // ---- reduce over h: in-wave (hl bits = lane bits 4,5), then cross-wave via LDS ----
    #pragma unroll
    for (int j = 0; j < 4; ++j) {
        pres[j] += __shfl_xor(pres[j], 16);
        pres[j] += __shfl_xor(pres[j], 32);
    }
    const int w  = tid >> 6;
    const int hl = (tid & 63) >> 4;
    if (hl == 0) {
        #pragma unroll
        for (int j = 0; j < 4; ++j) red[w * PT + pc * 4 + j] = pres[j];
    }
    __syncthreads();

    // ---- finalize: one thread per p ----
    if (tid < PT) {
        float res = 0.f;
        #pragma unroll
        for (int w2 = 0; w2 < 8; ++w2) res += red[w2 * PT + (tid & 15) * 4 + (tid >> 4)];

        float duu = 0.f;
        const float4* prow = p_lds + tid * RS;
        #pragma unroll
        for (int k = 0; k < 16; ++k) {
            float4 pv = prow[k], uv = u_lds[k];
            float dx = uv.x - pv.x, dy = uv.y - pv.y, dz = uv.z - pv.z, dw = uv.w - pv.w;
            duu += dx * dx + dy * dy + dz * dz + dw * dw;
        }
        const float dist_ui = fast_sqrt(duu + EPS);

        const float smooth2   = *sc_smooth;
        const float fs2       = *sc_force * smooth2;
        const float inv_denom = 1.f + __expf(fs2 - smooth2);
        const float lamb      = (*sc_global_lamb + user_lamb[uidx]) * inv_denom;

        const float o = fmaxf(0.f, dist_ui - lamb * res);
        const int pg = tile * PT + tid;
        if (pg < P) {
            const int pidx = pred_items[b * P + pg];
            out[b * P + pg] = *sc_alpha * o + *sc_beta * o * o + *sc_gamma
                              + user_bias[uidx] + item_bias[pidx];
        }
    }
}

extern "C" void kernel_launch(void* const* d_in, const int* in_sizes, int n_in,
                              void* d_out, int out_size, void* d_ws, size_t ws_size,
                              hipStream_t stream) {
    (void)in_sizes; (void)n_in; (void)d_ws; (void)ws_size; (void)out_size;
    ex2vec_kernel<<<dim3(B * TILES), dim3(NT), 0, stream>>>(
        (const int*)d_in[0],  (const int*)d_in[1],  (const int*)d_in[2],
        (const float*)d_in[3], (const float*)d_in[4],
        (const float*)d_in[5], (const float*)d_in[6],
        (const float*)d_in[7], (const float*)d_in[8], (const float*)d_in[9],
        (const float*)d_in[10], (const float*)d_in[11], (const float*)d_in[12],
        (const float*)d_in[13], (const float*)d_in[14], (const float*)d_in[15],
        (const float*)d_in[16], (float*)d_out);
}

// Round 4
// 17.125 us; speedup vs baseline: 2.7615x; 1.2416x over previous
//
#include <hip/hip_runtime.h>
#include <hip/hip_bf16.h>

#define EPS 1e-12f

constexpr int B = 32, P = 1000, H = 128, D = 64;
constexpr int NT = 256;                 // 4 waves; wave = 16 p-cols x 128 h-rows

typedef __attribute__((ext_vector_type(8))) short bf16x8;   // MFMA A/B frag (8 bf16)
typedef __attribute__((ext_vector_type(4))) float f32x4;

__device__ __forceinline__ float fast_rcp(float x)  { return __builtin_amdgcn_rcpf(x); }
__device__ __forceinline__ float fast_sqrt(float x) { return __builtin_amdgcn_sqrtf(x); }

__device__ __forceinline__ int pk2(float x, float y) {
    union { __hip_bfloat162 t; int i; } u;
    u.t = __float22bfloat162_rn(make_float2(x, y));   // v_cvt_pk_bf16_f32
    return u.i;
}
__device__ __forceinline__ bf16x8 cvt8(f32x4 a, f32x4 b) {
    union { bf16x8 v; int i[4]; } u;
    u.i[0] = pk2(a.x, a.y); u.i[1] = pk2(a.z, a.w);
    u.i[2] = pk2(b.x, b.y); u.i[3] = pk2(b.z, b.w);
    return u.v;
}
__device__ __forceinline__ float sum16(f32x4 a, f32x4 b, f32x4 c, f32x4 d) {
    return (a.x*a.x + a.y*a.y + a.z*a.z + a.w*a.w)
         + (b.x*b.x + b.y*b.y + b.z*b.z + b.w*b.w)
         + (c.x*c.x + c.y*c.y + c.z*c.z + c.w*c.w)
         + (d.x*d.x + d.y*d.y + d.z*d.z + d.w*d.w);
}

__global__ __launch_bounds__(NT)
void ex2vec_kernel(const int* __restrict__ user_index,
                   const int* __restrict__ pred_items,
                   const int* __restrict__ hist_items,
                   const float* __restrict__ hist_td,
                   const float* __restrict__ hist_w,
                   const float* __restrict__ emb_user,
                   const float* __restrict__ emb_item,
                   const float* __restrict__ user_lamb,
                   const float* __restrict__ user_bias,
                   const float* __restrict__ item_bias,
                   const float* __restrict__ sc_global_lamb,
                   const float* __restrict__ sc_alpha,
                   const float* __restrict__ sc_beta,
                   const float* __restrict__ sc_gamma,
                   const float* __restrict__ sc_cutoff,
                   const float* __restrict__ sc_smooth,
                   const float* __restrict__ sc_force,
                   float* __restrict__ out)
{
    __shared__ float hh[H];     // ||h_row||^2 (f32)
    __shared__ float td_s[H];   // (td+cutoff)^-0.5 * w

    const int b     = blockIdx.x >> 4;
    const int strip = blockIdx.x & 15;
    const int tid   = threadIdx.x;
    const int lane  = tid & 63;
    const int w     = tid >> 6;

    const int uidx = user_index[b];

    // ---- this lane's p column + fragment k-slice ----
    const int col = lane & 15;          // p col within wave / MFMA n-index
    const int kg  = lane >> 4;          // k-group: frag holds d = kg*8..kg*8+7 (+32 for half 1)
    const int pg  = strip * 64 + w * 16 + col;
    const int pgc = pg < P ? pg : P - 1;
    const int pidx = pred_items[b * P + pgc];

    const float* prow = emb_item + (size_t)pidx * D + kg * 8;
    f32x4 p0 = *(const f32x4*)(prow);
    f32x4 p1 = *(const f32x4*)(prow + 4);
    f32x4 p2 = *(const f32x4*)(prow + 32);
    f32x4 p3 = *(const f32x4*)(prow + 36);

    // ---- prologue: hh + td into LDS (waves 0-1), overlapped with p loads ----
    const float cutoff = *sc_cutoff;
    if (tid < H) {
        const int hidx = hist_items[b * H + tid];
        const f32x4* row = (const f32x4*)(emb_item + (size_t)hidx * D);
        float s = 0.f;
        #pragma unroll
        for (int k = 0; k < 16; ++k) {
            f32x4 v = row[k];
            s += v.x*v.x + v.y*v.y + v.z*v.z + v.w*v.w;
        }
        hh[tid]   = s;
        td_s[tid] = hist_w[b*H + tid] * __frsqrt_rn(hist_td[b*H + tid] + cutoff);
    }

    // ---- pp for this col: in-wave reduce over the 4 k-groups ----
    float ppart = sum16(p0, p1, p2, p3);
    ppart += __shfl_xor(ppart, 16);
    ppart += __shfl_xor(ppart, 32);
    const float pp = ppart;

    const bf16x8 bfr0 = cvt8(p0, p1);   // B frag, k-half 0 (d 0..31)
    const bf16x8 bfr1 = cvt8(p2, p3);   // B frag, k-half 1 (d 32..63)

    const float smooth = *sc_smooth;
    const float fs     = *sc_force * smooth;

    __syncthreads();

    // ---- 8 h-tiles of 16: gather A from global, MFMA, fused elementwise ----
    float pres = 0.f;
    #pragma unroll
    for (int t = 0; t < 8; ++t) {
        const int hidx = hist_items[b*H + t*16 + col];      // A row = col (lane&15)
        const float* hrp = emb_item + (size_t)hidx * D + kg * 8;
        f32x4 a0 = *(const f32x4*)(hrp);
        f32x4 a1 = *(const f32x4*)(hrp + 4);
        f32x4 a2 = *(const f32x4*)(hrp + 32);
        f32x4 a3 = *(const f32x4*)(hrp + 36);
        const bf16x8 af0 = cvt8(a0, a1);
        const bf16x8 af1 = cvt8(a2, a3);
        f32x4 acc = {0.f, 0.f, 0.f, 0.f};
        acc = __builtin_amdgcn_mfma_f32_16x16x32_bf16(af0, bfr0, acc, 0, 0, 0);
        acc = __builtin_amdgcn_mfma_f32_16x16x32_bf16(af1, bfr1, acc, 0, 0, 0);
        // D[row][col]: row = t*16 + kg*4 + j, col = lane&15
        #pragma unroll
        for (int j = 0; j < 4; ++j) {
            const int r = t*16 + kg*4 + j;
            const float sq   = hh[r] + pp - 2.f * acc[j];
            const float dist = fast_sqrt(fmaxf(sq, 0.f) + EPS);
            const float x    = smooth * fast_rcp(1.f + dist) - fs;
            pres += td_s[r] * fast_rcp(1.f + __expf(-x));
        }
    }
    pres += __shfl_xor(pres, 16);       // sum over k-groups -> all 128 h
    pres += __shfl_xor(pres, 32);

    // ---- dist_ui cooperative (f32 exact path) ----
    const float* urow = emb_user + (size_t)uidx * D + kg * 8;
    f32x4 u0 = *(const f32x4*)(urow);
    f32x4 u1 = *(const f32x4*)(urow + 4);
    f32x4 u2 = *(const f32x4*)(urow + 32);
    f32x4 u3 = *(const f32x4*)(urow + 36);
    f32x4 d0 = u0 - p0, d1 = u1 - p1, d2 = u2 - p2, d3 = u3 - p3;
    float dpart = sum16(d0, d1, d2, d3);
    dpart += __shfl_xor(dpart, 16);
    dpart += __shfl_xor(dpart, 32);

    if (lane < 16 && pg < P) {
        const float inv_denom = 1.f + __expf(fs - smooth);
        const float lamb      = (*sc_global_lamb + user_lamb[uidx]) * inv_denom;
        const float dist_ui   = fast_sqrt(dpart + EPS);
        const float o = fmaxf(0.f, dist_ui - lamb * pres);
        out[b*P + pg] = (*sc_alpha) * o + (*sc_beta) * o * o + (*sc_gamma)
                        + user_bias[uidx] + item_bias[pidx];
    }
}

extern "C" void kernel_launch(void* const* d_in, const int* in_sizes, int n_in,
                              void* d_out, int out_size, void* d_ws, size_t ws_size,
                              hipStream_t stream) {
    (void)in_sizes; (void)n_in; (void)d_ws; (void)ws_size; (void)out_size;
    ex2vec_kernel<<<dim3(B * 16), dim3(NT), 0, stream>>>(
        (const int*)d_in[0],  (const int*)d_in[1],  (const int*)d_in[2],
        (const float*)d_in[3], (const float*)d_in[4],
        (const float*)d_in[5], (const float*)d_in[6],
        (const float*)d_in[7], (const float*)d_in[8], (const float*)d_in[9],
        (const float*)d_in[10], (const float*)d_in[11], (const float*)d_in[12],
        (const float*)d_in[13], (const float*)d_in[14], (const float*)d_in[15],
        (const float*)d_in[16], (float*)d_out);
}